// Round 1
// baseline (1472.490 us; speedup 1.0000x reference)
//
#include <hip/hip_runtime.h>

typedef _Float16 half8 __attribute__((ext_vector_type(8)));
typedef _Float16 half4 __attribute__((ext_vector_type(4)));
typedef float floatx4 __attribute__((ext_vector_type(4)));

// Problem constants
// B=4096 windows, N=64 tokens (8x8), C=192, NH=6, HD=32, KS=5, KB=8
// ws layout (bytes):
//   Wt  : _Float16 [768][192]  @ 0        (294912 B)   Wt[n][k] = [wq|wkv][k][n]
//   Pt  : _Float16 [192][192]  @ 294912   (73728 B)    Pt[n][k] = proj_w[k][n]
//   biasA: float   [6][64][64] @ 368640   (98304 B)    biasA[h][i][j]
// total 466944 B

__global__ __launch_bounds__(512) void prep_kernel(
    const float* __restrict__ wq, const float* __restrict__ wkv,
    const float* __restrict__ proj_w, const float* __restrict__ rpb,
    const int* __restrict__ rel,
    _Float16* __restrict__ Wt, _Float16* __restrict__ Pt,
    float* __restrict__ biasA)
{
    int idx = blockIdx.x * 512 + threadIdx.x;
    if (idx < 147456) {                       // 768*192
        int n = idx / 192, kk = idx % 192;
        float v = (n < 192) ? wq[kk * 192 + n] : wkv[kk * 576 + (n - 192)];
        Wt[idx] = (_Float16)v;
    } else if (idx < 184320) {                // + 192*192
        int i = idx - 147456;
        int n = i / 192, kk = i % 192;
        Pt[i] = (_Float16)proj_w[kk * 192 + n];
    } else if (idx < 208896) {                // + 6*4096
        int i = idx - 184320;
        int h = i >> 12;
        int pos = i & 4095;
        biasA[i] = rpb[rel[pos] * 6 + h];
    }
}

// LDS layout (in _Float16 units unless noted):
//  sQ   [6][64][40]   off 0      (15360 h)  q[h][m][d], stride 40 (16B aligned, 2-way banks)
//  sK   [6][64][40]   off 15360  (15360 h)  k[h][m][d]; reused as out_pre[h][m][d]
//  sVT  [6][32][72]   off 30720  (13824 h)  vT[h][d][m]
//  sVR  [192][72]     off 44544  (13824 h)  vr[c][n]; reused as position [64][198] (pos[n][c])
//  sX   [64][200]     off 58368  (12800 h)  x f16; reused as p[192][66]; then scores f32[64][64] + P f16[64][72]
//  sBias float[1344]  byte off 142336       (bqkv 768 | proj_b 192 | dw_b 192 | pw_b 192)
// total bytes = 142336 + 5376 = 147712

__global__ __launch_bounds__(512) void wa_main(
    const float* __restrict__ xg,
    const float* __restrict__ bq, const float* __restrict__ bkv,
    const float* __restrict__ dw_w, const float* __restrict__ pw_w,
    const float* __restrict__ proj_bg,
    const _Float16* __restrict__ Wt, const _Float16* __restrict__ Pt,
    const float* __restrict__ biasA,
    const float* __restrict__ dw_bg, const float* __restrict__ pw_bg,
    float* __restrict__ outg)
{
    extern __shared__ unsigned char smem[];
    _Float16* sQ   = (_Float16*)smem;
    _Float16* sK   = sQ + 15360;
    _Float16* sVT  = sQ + 30720;
    _Float16* sVR  = sQ + 44544;
    _Float16* sX   = sQ + 58368;
    float*    sBias = (float*)(smem + 142336);
    // aliases
    float*    sScores = (float*)sX;          // [64][64] f32
    _Float16* sPmat   = sX + 8192;           // [64][72] f16 (byte off 16384, 16B aligned rows: 144B stride)
    _Float16* sP      = sX;                  // [192][66] f16 (dw-conv out)
    _Float16* sPos    = sVR;                 // [64][198] f16 (pos[n][c])
    _Float16* sOutp   = sK;                  // [6][64][40] f16 (attn+pos, pre-proj)

    const int b    = blockIdx.x;
    const int tid  = threadIdx.x;
    const int lane = tid & 63;
    const int wv   = tid >> 6;
    const int mrow = lane & 15;   // m (A/D row base) or n (B/D col)
    const int kq   = lane >> 4;   // quad: k-offset kq*8 for A/B, row-offset kq*4 for C/D

    // ---------------- Phase 0: stage x -> f16 LDS, biases -> LDS ----------------
    const float* xb = xg + (size_t)b * 12288;
    #pragma unroll
    for (int it = 0; it < 6; ++it) {
        int f4  = it * 512 + tid;            // 0..3071 float4s
        int row = f4 / 48;
        int col = (f4 % 48) * 4;
        float4 v = ((const float4*)xb)[f4];
        _Float16* dst = sX + row * 200 + col;
        dst[0] = (_Float16)v.x; dst[1] = (_Float16)v.y;
        dst[2] = (_Float16)v.z; dst[3] = (_Float16)v.w;
    }
    for (int idx = tid; idx < 1344; idx += 512) {
        float v;
        if      (idx < 192)  v = bq[idx];
        else if (idx < 768)  v = bkv[idx - 192];
        else if (idx < 960)  v = proj_bg[idx - 768];
        else if (idx < 1152) v = dw_bg[idx - 960];
        else                 v = pw_bg[idx - 1152];
        sBias[idx] = v;
    }
    __syncthreads();

    // ---------------- Phase 1: QKV GEMM (M=64, N=768, K=192) ----------------
    {
        half8 af[4][6];
        #pragma unroll
        for (int mt = 0; mt < 4; ++mt)
            #pragma unroll
            for (int ks = 0; ks < 6; ++ks)
                af[mt][ks] = *(const half8*)(sX + (mt * 16 + mrow) * 200 + ks * 32 + kq * 8);

        #pragma unroll 1
        for (int it = 0; it < 6; ++it) {
            int nt   = it * 8 + wv;          // 0..47
            int ncol = nt * 16 + mrow;
            half8 bf[6];
            const _Float16* wp = Wt + ncol * 192 + kq * 8;
            #pragma unroll
            for (int ks = 0; ks < 6; ++ks) bf[ks] = *(const half8*)(wp + ks * 32);
            float bv = sBias[ncol];
            #pragma unroll
            for (int mt = 0; mt < 4; ++mt) {
                floatx4 acc = {bv, bv, bv, bv};
                #pragma unroll
                for (int ks = 0; ks < 6; ++ks)
                    acc = __builtin_amdgcn_mfma_f32_16x16x32_f16(af[mt][ks], bf[ks], acc, 0, 0, 0);
                int m0 = mt * 16 + kq * 4;
                if (nt < 12) {                         // q: cols 0..191
                    int h = ncol >> 5, d = ncol & 31;
                    _Float16* q = sQ + (h * 64 + m0) * 40 + d;
                    #pragma unroll
                    for (int r = 0; r < 4; ++r) q[r * 40] = (_Float16)acc[r];
                } else if (nt < 24) {                  // k: cols 192..383
                    int cc = ncol - 192; int h = cc >> 5, d = cc & 31;
                    _Float16* kk = sK + (h * 64 + m0) * 40 + d;
                    #pragma unroll
                    for (int r = 0; r < 4; ++r) kk[r * 40] = (_Float16)acc[r];
                } else if (nt < 36) {                  // v: cols 384..575 -> vT[h][d][m]
                    int cc = ncol - 384; int h = cc >> 5, d = cc & 31;
                    half4 p;
                    #pragma unroll
                    for (int r = 0; r < 4; ++r) p[r] = (_Float16)acc[r];
                    *(half4*)(sVT + (h * 32 + d) * 72 + m0) = p;
                } else {                               // vr: cols 576..767 -> vr[c][n]
                    int c = ncol - 576;
                    half4 p;
                    #pragma unroll
                    for (int r = 0; r < 4; ++r) p[r] = (_Float16)acc[r];
                    *(half4*)(sVR + c * 72 + m0) = p;
                }
            }
        }
    }
    __syncthreads();

    // ---------------- Phase 2a: depthwise 5x5 conv (SAME) on vr ----------------
    #pragma unroll 1
    for (int it = 0; it < 24; ++it) {
        int cu = __builtin_amdgcn_readfirstlane(it * 8 + wv);  // wave-uniform channel
        int n = lane, i = n >> 3, j = n & 7;
        float acc = sBias[960 + cu];
        const float* wc = dw_w + cu * 25;
        const _Float16* vrow = sVR + cu * 72;
        #pragma unroll
        for (int di = 0; di < 5; ++di) {
            int ii = i + di - 2;
            bool vi = (ii >= 0) & (ii < 8);
            #pragma unroll
            for (int dj = 0; dj < 5; ++dj) {
                int jj = j + dj - 2;
                bool ok = vi & (jj >= 0) & (jj < 8);
                int off = ok ? (ii * 8 + jj) : 0;
                float v = (float)vrow[off];
                acc = fmaf(ok ? v : 0.0f, wc[di * 5 + dj], acc);
            }
        }
        sP[cu * 66 + n] = (_Float16)acc;   // overwrites sX region (x is dead)
    }
    __syncthreads();

    // ---------------- Phase 2b: grouped 1x1 conv -> position ----------------
    #pragma unroll 1
    for (int it = 0; it < 24; ++it) {
        int cu = __builtin_amdgcn_readfirstlane(it * 8 + wv);
        int g = cu >> 5;
        int n = lane;
        float acc = sBias[1152 + cu];
        const float* wc = pw_w + cu * 32;
        const _Float16* pg = sP + (g * 32) * 66 + n;
        #pragma unroll
        for (int d = 0; d < 32; ++d)
            acc = fmaf((float)pg[d * 66], wc[d], acc);
        sPos[n * 198 + cu] = (_Float16)acc;  // overwrites sVR region (vr is dead)
    }
    __syncthreads();

    // ---------------- Phase 3: attention, per head ----------------
    const float scale = 0.17677669529663687f;  // 32^-0.5
    #pragma unroll 1
    for (int h = 0; h < 6; ++h) {
        // (a) scores = q @ k^T * scale + bias   (M=64,N=64,K=32): 16 tiles, 2/wave
        #pragma unroll
        for (int tt = 0; tt < 2; ++tt) {
            int tile = wv * 2 + tt;
            int mt = tile >> 2, nt2 = tile & 3;
            half8 aq = *(const half8*)(sQ + (h * 64 + mt * 16 + mrow) * 40 + kq * 8);
            half8 bk = *(const half8*)(sK + (h * 64 + nt2 * 16 + mrow) * 40 + kq * 8);
            floatx4 sc = {0.f, 0.f, 0.f, 0.f};
            sc = __builtin_amdgcn_mfma_f32_16x16x32_f16(aq, bk, sc, 0, 0, 0);
            int ncol2 = nt2 * 16 + mrow;
            int m0 = mt * 16 + kq * 4;
            const float* bb = biasA + h * 4096;
            #pragma unroll
            for (int r = 0; r < 4; ++r)
                sScores[(m0 + r) * 64 + ncol2] = sc[r] * scale + bb[(m0 + r) * 64 + ncol2];
        }
        __syncthreads();
        // (b) softmax over rows (8 rows/wave, lane = column)
        #pragma unroll
        for (int rr = 0; rr < 8; ++rr) {
            int row = wv * 8 + rr;
            float v = sScores[row * 64 + lane];
            float mx = v;
            #pragma unroll
            for (int off = 32; off >= 1; off >>= 1) mx = fmaxf(mx, __shfl_xor(mx, off));
            float e = __expf(v - mx);
            float sm = e;
            #pragma unroll
            for (int off = 32; off >= 1; off >>= 1) sm += __shfl_xor(sm, off);
            sPmat[row * 72 + lane] = (_Float16)(e / sm);
        }
        __syncthreads();
        // (c) out_pre[h] = P @ v + position  (M=64,N=32,K=64): 8 tiles, 1/wave
        {
            int mt = wv >> 1, ntd = wv & 1;
            const _Float16* pr = sPmat + (mt * 16 + mrow) * 72 + kq * 8;
            half8 ap0 = *(const half8*)(pr);
            half8 ap1 = *(const half8*)(pr + 32);
            const _Float16* vr2 = sVT + (h * 32 + ntd * 16 + mrow) * 72 + kq * 8;
            half8 bv0 = *(const half8*)(vr2);
            half8 bv1 = *(const half8*)(vr2 + 32);
            int dcol = ntd * 16 + mrow;
            int cc = h * 32 + dcol;
            int m0 = mt * 16 + kq * 4;
            floatx4 acc;
            #pragma unroll
            for (int r = 0; r < 4; ++r) acc[r] = (float)sPos[(m0 + r) * 198 + cc];
            acc = __builtin_amdgcn_mfma_f32_16x16x32_f16(ap0, bv0, acc, 0, 0, 0);
            acc = __builtin_amdgcn_mfma_f32_16x16x32_f16(ap1, bv1, acc, 0, 0, 0);
            _Float16* op = sOutp + (h * 64 + m0) * 40 + dcol;  // sK region reuse (k[h] dead)
            #pragma unroll
            for (int r = 0; r < 4; ++r) op[r * 40] = (_Float16)acc[r];
        }
    }
    __syncthreads();

    // ---------------- Phase 4: proj GEMM (M=64, N=192, K=192) ----------------
    {
        half8 af[4][6];
        #pragma unroll
        for (int mt = 0; mt < 4; ++mt)
            #pragma unroll
            for (int ks = 0; ks < 6; ++ks)
                af[mt][ks] = *(const half8*)(sOutp + (ks * 64 + mt * 16 + mrow) * 40 + kq * 8);

        float* og = outg + (size_t)b * 12288;
        #pragma unroll 1
        for (int it = 0; it < 6; ++it) {
            int tile = it * 8 + wv;          // 0..47
            int mt = tile / 12, nt = tile % 12;
            int ncol = nt * 16 + mrow;
            half8 bf[6];
            const _Float16* pp = Pt + ncol * 192 + kq * 8;
            #pragma unroll
            for (int ks = 0; ks < 6; ++ks) bf[ks] = *(const half8*)(pp + ks * 32);
            float bv = sBias[768 + ncol];
            floatx4 acc = {bv, bv, bv, bv};
            #pragma unroll
            for (int ks = 0; ks < 6; ++ks)
                acc = __builtin_amdgcn_mfma_f32_16x16x32_f16(af[mt][ks], bf[ks], acc, 0, 0, 0);
            int m0 = mt * 16 + kq * 4;
            #pragma unroll
            for (int r = 0; r < 4; ++r)
                og[(m0 + r) * 192 + ncol] = acc[r];
        }
    }
}

extern "C" void kernel_launch(void* const* d_in, const int* in_sizes, int n_in,
                              void* d_out, int out_size, void* d_ws, size_t ws_size,
                              hipStream_t stream) {
    (void)in_sizes; (void)n_in; (void)out_size; (void)ws_size;
    const float* x      = (const float*)d_in[0];
    const float* wq     = (const float*)d_in[1];
    const float* bq     = (const float*)d_in[2];
    const float* wkv    = (const float*)d_in[3];
    const float* bkv    = (const float*)d_in[4];
    const float* rpb    = (const float*)d_in[5];
    const int*   rel    = (const int*)d_in[6];
    const float* dw_w   = (const float*)d_in[7];
    const float* dw_b   = (const float*)d_in[8];
    const float* pw_w   = (const float*)d_in[9];
    const float* pw_b   = (const float*)d_in[10];
    const float* proj_w = (const float*)d_in[11];
    const float* proj_b = (const float*)d_in[12];

    _Float16* Wt    = (_Float16*)d_ws;
    _Float16* Pt    = Wt + 147456;
    float*    biasA = (float*)((char*)d_ws + 368640);

    prep_kernel<<<408, 512, 0, stream>>>(wq, wkv, proj_w, rpb, rel, Wt, Pt, biasA);
    wa_main<<<4096, 512, 147712, stream>>>(x, bq, bkv, dw_w, pw_w, proj_b,
                                           Wt, Pt, biasA, dw_b, pw_b, (float*)d_out);
}

// Round 2
// 600.093 us; speedup vs baseline: 2.4538x; 2.4538x over previous
//
#include <hip/hip_runtime.h>

typedef _Float16 half8 __attribute__((ext_vector_type(8)));
typedef _Float16 half4 __attribute__((ext_vector_type(4)));
typedef _Float16 half2 __attribute__((ext_vector_type(2)));
typedef float floatx4 __attribute__((ext_vector_type(4)));

union H8 { half8 h8; half2 h2[4]; int i[4]; };

// Problem constants: B=4096 windows, N=64 tokens (8x8), C=192, NH=6, HD=32, KS=5
//
// ws layout (bytes) -- everything pre-swizzled into MFMA fragment order:
//   WtF  : f16 [48 nt][6 ks][64 lane][8]  @ 0       (294912 B)  qkv weights (B-frags)
//   PtF  : f16 [12 nt][6 ks][64 lane][8]  @ 294912  ( 73728 B)  proj weights (B-frags)
//   biasF: f32 [6 h][4 mt'][4 ntq][64 lane][4 r] @ 368640 (98304 B)  attn bias in S^T C-frag order
//   dwF  : f16 [6 g][4 kq][25 tap][8 ch]  @ 466944  (  9600 B)  depthwise weights
//   dwbF : f16 [6 g][4 kq][8 ch]          @ 476544  (   384 B)  depthwise bias
//   pwF  : f16 [6 g][2 ntc][64 lane][8]   @ 476928  ( 12288 B)  1x1 grouped weights (B-frags)
// total 489216 B

__global__ __launch_bounds__(512) void prep_kernel(
    const float* __restrict__ wq, const float* __restrict__ wkv,
    const float* __restrict__ proj_w, const float* __restrict__ rpb,
    const int* __restrict__ rel,
    const float* __restrict__ dw_w, const float* __restrict__ dw_b,
    const float* __restrict__ pw_w,
    _Float16* __restrict__ WtF, _Float16* __restrict__ PtF,
    float* __restrict__ biasF, _Float16* __restrict__ dwF,
    _Float16* __restrict__ dwbF, _Float16* __restrict__ pwF)
{
    int idx = blockIdx.x * 512 + threadIdx.x;
    if (idx < 147456) {                                   // WtF
        int j = idx & 7, lane = (idx >> 3) & 63, t = idx >> 9;
        int ks = t % 6, nt = t / 6;
        int k = ks * 32 + (lane >> 4) * 8 + j;
        int n = nt * 16 + (lane & 15);
        float v = (n < 192) ? wq[k * 192 + n] : wkv[k * 576 + (n - 192)];
        WtF[idx] = (_Float16)v;
    } else if (idx < 184320) {                            // PtF
        int i2 = idx - 147456;
        int j = i2 & 7, lane = (i2 >> 3) & 63, t = i2 >> 9;
        int ks = t % 6, nt = t / 6;
        int k = ks * 32 + (lane >> 4) * 8 + j;
        int n = nt * 16 + (lane & 15);
        PtF[i2] = (_Float16)proj_w[k * 192 + n];
    } else if (idx < 208896) {                            // biasF (f32)
        int i2 = idx - 184320;
        int r = i2 & 3, lane = (i2 >> 2) & 63, t = i2 >> 8;
        int ntq = t & 3, mt = (t >> 2) & 3, h = t >> 4;
        int m = mt * 16 + (lane >> 4) * 4 + r;            // key token (S^T row)
        int n = ntq * 16 + (lane & 15);                   // query token (S^T col)
        biasF[i2] = rpb[rel[n * 64 + m] * 6 + h];
    } else if (idx < 213696) {                            // dwF
        int i2 = idx - 208896;
        int j = i2 & 7, t = i2 >> 3;
        int tap = t % 25, gk = t / 25;
        int c = (gk >> 2) * 32 + (gk & 3) * 8 + j;
        dwF[i2] = (_Float16)dw_w[c * 25 + tap];
    } else if (idx < 213888) {                            // dwbF
        int i2 = idx - 213696;
        int j = i2 & 7, gk = i2 >> 3;
        int c = (gk >> 2) * 32 + (gk & 3) * 8 + j;
        dwbF[i2] = (_Float16)dw_b[c];
    } else if (idx < 220032) {                            // pwF
        int i2 = idx - 213888;
        int j = i2 & 7, lane = (i2 >> 3) & 63, t = i2 >> 9;
        int ntc = t & 1, g = t >> 1;
        int oc = g * 32 + ntc * 16 + (lane & 15);
        int ic = (lane >> 4) * 8 + j;
        pwF[i2] = (_Float16)pw_w[oc * 32 + ic];
    }
}

// LDS layout (offsets in _Float16 units unless noted):
//  sX   [64][200]  @ 0      (12800 h) x staged f16
//  sQ   [6][64][40]@ 12800  (15360 h) q*scale
//  sK   [6][64][40]@ 28160  (15360 h)
//  sVT  [6][32][72]@ 43520  (13824 h) v^T[h][d][m]
//  sVR  [64][200]  @ 57344  (12800 h) v_r[n][c]; reused as out_pre[n][c] (attn+pos)
//  zero16          @ 70144  (8 h)     16 B of zeros (conv OOB reads)
//  sBias f32[960]  @ byte 140304      (qkv bias 768 | proj_b 192)
//  sOut32 f32[64][196] aliases sQ+sK (byte 25600..) for coalesced copy-out
// total = 144144 B  (1 block/CU)

#define XO   0
#define QO   12800
#define KO   28160
#define VTO  43520
#define VRO  57344
#define ZO   70144

__global__ __launch_bounds__(512, 2) void wa_main(
    const float* __restrict__ xg,
    const float* __restrict__ bq, const float* __restrict__ bkv,
    const float* __restrict__ proj_bg, const float* __restrict__ pw_b,
    const _Float16* __restrict__ WtF, const _Float16* __restrict__ PtF,
    const float* __restrict__ biasF,
    const _Float16* __restrict__ dwF, const _Float16* __restrict__ dwbF,
    const _Float16* __restrict__ pwF,
    float* __restrict__ outg)
{
    extern __shared__ unsigned char smem[];
    _Float16* sHalf = (_Float16*)smem;
    float* sBias = (float*)(smem + 140304);
    float* sOut32 = (float*)(smem + 25600);   // aliases sQ+sK

    const int b    = blockIdx.x;
    const int tid  = threadIdx.x;
    const int lane = tid & 63;
    const int wv   = tid >> 6;
    const int mrow = lane & 15;
    const int kq   = lane >> 4;
    const float scale = 0.17677669529663687f;   // 32^-0.5

    // ---------------- Phase 0: stage x -> f16 LDS; biases; zero page ----------------
    const float* xb = xg + (size_t)b * 12288;
    #pragma unroll
    for (int it = 0; it < 6; ++it) {
        int f4  = it * 512 + tid;
        int row = f4 / 48;
        int col = (f4 % 48) * 4;
        float4 v = ((const float4*)xb)[f4];
        _Float16* dst = sHalf + XO + row * 200 + col;
        dst[0] = (_Float16)v.x; dst[1] = (_Float16)v.y;
        dst[2] = (_Float16)v.z; dst[3] = (_Float16)v.w;
    }
    for (int idx = tid; idx < 960; idx += 512) {
        float v;
        if      (idx < 192) v = bq[idx];
        else if (idx < 768) v = bkv[idx - 192];
        else                v = proj_bg[idx - 768];
        sBias[idx] = v;
    }
    if (tid < 8) sHalf[ZO + tid] = (_Float16)0.0f;
    __syncthreads();   // barrier 1

    // ---------------- Phase 1: QKV GEMM (M=64, N=768, K=192) ----------------
    {
        half8 af[4][6];
        #pragma unroll
        for (int mt = 0; mt < 4; ++mt)
            #pragma unroll
            for (int ks = 0; ks < 6; ++ks)
                af[mt][ks] = *(const half8*)(sHalf + XO + (mt * 16 + mrow) * 200 + ks * 32 + kq * 8);

        #pragma unroll 1
        for (int it = 0; it < 6; ++it) {
            int nt   = it * 8 + wv;                  // 0..47
            int ncol = nt * 16 + mrow;
            half8 bf[6];
            #pragma unroll
            for (int ks = 0; ks < 6; ++ks)
                bf[ks] = ((const half8*)WtF)[(nt * 6 + ks) * 64 + lane];   // coalesced 1 KB/instr
            float bv = sBias[ncol];
            #pragma unroll
            for (int mt = 0; mt < 4; ++mt) {
                floatx4 acc = {bv, bv, bv, bv};
                #pragma unroll
                for (int ks = 0; ks < 6; ++ks)
                    acc = __builtin_amdgcn_mfma_f32_16x16x32_f16(af[mt][ks], bf[ks], acc, 0, 0, 0);
                int m0 = mt * 16 + kq * 4;
                if (nt < 12) {                        // q (scaled)
                    int h = ncol >> 5, d = ncol & 31;
                    _Float16* q = sHalf + QO + (h * 64 + m0) * 40 + d;
                    #pragma unroll
                    for (int r = 0; r < 4; ++r) q[r * 40] = (_Float16)(acc[r] * scale);
                } else if (nt < 24) {                 // k
                    int cc = ncol - 192; int h = cc >> 5, d = cc & 31;
                    _Float16* kk = sHalf + KO + (h * 64 + m0) * 40 + d;
                    #pragma unroll
                    for (int r = 0; r < 4; ++r) kk[r * 40] = (_Float16)acc[r];
                } else if (nt < 36) {                 // v -> vT[h][d][m]
                    int cc = ncol - 384; int h = cc >> 5, d = cc & 31;
                    half4 p;
                    #pragma unroll
                    for (int r = 0; r < 4; ++r) p[r] = (_Float16)acc[r];
                    *(half4*)(sHalf + VTO + (h * 32 + d) * 72 + m0) = p;
                } else {                              // v_r -> [n][c] token-major
                    int c = ncol - 576;
                    #pragma unroll
                    for (int r = 0; r < 4; ++r)
                        sHalf[VRO + (m0 + r) * 200 + c] = (_Float16)acc[r];
                }
            }
        }
    }
    __syncthreads();   // barrier 2

    // ---------------- Phase 2+3: conv branch + attention, per-wave (wave = head) ----------------
    if (wv < 6) {
        const int h = wv;

        // --- 2a: depthwise 5x5 (SAME), packed f16; output lands in A-frag layout ---
        const int cb32 = h * 32 + kq * 8;           // global channel base for this lane
        const half8* dwFp = (const half8*)dwF + (h * 4 + kq) * 25;
        H8 bini; bini.h8 = ((const half8*)dwbF)[h * 4 + kq];
        half2 cacc[4][4];
        #pragma unroll
        for (int mt = 0; mt < 4; ++mt)
            #pragma unroll
            for (int p = 0; p < 4; ++p) cacc[mt][p] = bini.h2[p];

        int ni[4], nj[4];
        #pragma unroll
        for (int mt = 0; mt < 4; ++mt) { int n = mt * 16 + mrow; ni[mt] = n >> 3; nj[mt] = n & 7; }

        #pragma unroll 5
        for (int t = 0; t < 25; ++t) {
            H8 w; w.h8 = dwFp[t];
            int di = t / 5 - 2, dj = t % 5 - 2;
            #pragma unroll
            for (int mt = 0; mt < 4; ++mt) {
                int ii = ni[mt] + di, jj = nj[mt] + dj;
                bool ok = ((unsigned)ii < 8u) & ((unsigned)jj < 8u);
                int off = ok ? (VRO + ((ii << 3) + jj) * 200 + cb32) : ZO;
                H8 d; d.h8 = *(const half8*)(sHalf + off);
                #pragma unroll
                for (int p = 0; p < 4; ++p) cacc[mt][p] += d.h2[p] * w.h2[p];
            }
        }
        half8 dwA[4];
        #pragma unroll
        for (int mt = 0; mt < 4; ++mt) {
            H8 u;
            #pragma unroll
            for (int p = 0; p < 4; ++p) u.h2[p] = cacc[mt][p];
            dwA[mt] = u.h8;
        }

        // --- 2b: grouped 1x1 conv via MFMA; D directly seeds the PV accumulator ---
        floatx4 accPV[4][2];
        #pragma unroll
        for (int ntc = 0; ntc < 2; ++ntc) {
            half8 pwB = ((const half8*)pwF)[(h * 2 + ntc) * 64 + lane];
            float pb = pw_b[h * 32 + ntc * 16 + mrow];
            #pragma unroll
            for (int mt = 0; mt < 4; ++mt) {
                floatx4 acc = {pb, pb, pb, pb};
                accPV[mt][ntc] = __builtin_amdgcn_mfma_f32_16x16x32_f16(dwA[mt], pwB, acc, 0, 0, 0);
            }
        }

        // --- 3a: S^T = K . Q^T (so softmax is a column reduce) ---
        half8 aK[4], bQ[4];
        #pragma unroll
        for (int t4 = 0; t4 < 4; ++t4) {
            aK[t4] = *(const half8*)(sHalf + KO + (h * 64 + t4 * 16 + mrow) * 40 + kq * 8);
            bQ[t4] = *(const half8*)(sHalf + QO + (h * 64 + t4 * 16 + mrow) * 40 + kq * 8);
        }
        floatx4 st[4][4];
        #pragma unroll
        for (int mtk = 0; mtk < 4; ++mtk)
            #pragma unroll
            for (int ntq = 0; ntq < 4; ++ntq) {
                floatx4 bb = *(const floatx4*)(biasF + (((h * 4 + mtk) * 4 + ntq) * 64 + lane) * 4);
                st[mtk][ntq] = __builtin_amdgcn_mfma_f32_16x16x32_f16(aK[mtk], bQ[ntq], bb, 0, 0, 0);
            }

        // --- 3b: softmax over keys (S^T rows) = per-lane 16 vals + shfl over kq bits ---
        #pragma unroll
        for (int ntq = 0; ntq < 4; ++ntq) {
            float mx = st[0][ntq][0];
            #pragma unroll
            for (int mtk = 0; mtk < 4; ++mtk)
                #pragma unroll
                for (int r = 0; r < 4; ++r) mx = fmaxf(mx, st[mtk][ntq][r]);
            mx = fmaxf(mx, __shfl_xor(mx, 16));
            mx = fmaxf(mx, __shfl_xor(mx, 32));
            float sm = 0.0f;
            #pragma unroll
            for (int mtk = 0; mtk < 4; ++mtk)
                #pragma unroll
                for (int r = 0; r < 4; ++r) {
                    float e = __expf(st[mtk][ntq][r] - mx);
                    st[mtk][ntq][r] = e;
                    sm += e;
                }
            sm += __shfl_xor(sm, 16);
            sm += __shfl_xor(sm, 32);
            float inv = 1.0f / sm;
            #pragma unroll
            for (int mtk = 0; mtk < 4; ++mtk)
                #pragma unroll
                for (int r = 0; r < 4; ++r) st[mtk][ntq][r] *= inv;
        }

        // --- 3c: pack P^T (C-layout) and bpermute into PV A-frags (no LDS, no barrier) ---
        int pk[4][4][2];
        #pragma unroll
        for (int mtk = 0; mtk < 4; ++mtk)
            #pragma unroll
            for (int ntq = 0; ntq < 4; ++ntq) {
                union { _Float16 hh[2]; int ii; } u0, u1;
                u0.hh[0] = (_Float16)st[mtk][ntq][0]; u0.hh[1] = (_Float16)st[mtk][ntq][1];
                u1.hh[0] = (_Float16)st[mtk][ntq][2]; u1.hh[1] = (_Float16)st[mtk][ntq][3];
                pk[mtk][ntq][0] = u0.ii;
                pk[mtk][ntq][1] = u1.ii;
            }
        const int idxA = ((kq & 1) * 32 + mrow) * 4;
        const int idxB = idxA + 64;
        const bool sel = (kq >= 2);
        half8 aP[4][2];
        #pragma unroll
        for (int ks = 0; ks < 2; ++ks)
            #pragma unroll
            for (int mtq = 0; mtq < 4; ++mtq) {
                int s0 = ks * 2, s1 = ks * 2 + 1;
                int a0 = __builtin_amdgcn_ds_bpermute(idxA, pk[s0][mtq][0]);
                int b0 = __builtin_amdgcn_ds_bpermute(idxA, pk[s1][mtq][0]);
                int a1 = __builtin_amdgcn_ds_bpermute(idxA, pk[s0][mtq][1]);
                int b1 = __builtin_amdgcn_ds_bpermute(idxA, pk[s1][mtq][1]);
                int a2 = __builtin_amdgcn_ds_bpermute(idxB, pk[s0][mtq][0]);
                int b2 = __builtin_amdgcn_ds_bpermute(idxB, pk[s1][mtq][0]);
                int a3 = __builtin_amdgcn_ds_bpermute(idxB, pk[s0][mtq][1]);
                int b3 = __builtin_amdgcn_ds_bpermute(idxB, pk[s1][mtq][1]);
                H8 u;
                u.i[0] = sel ? b0 : a0;
                u.i[1] = sel ? b1 : a1;
                u.i[2] = sel ? b2 : a2;
                u.i[3] = sel ? b3 : a3;
                aP[mtq][ks] = u.h8;
            }

        // --- 3d: PV (+position via accPV init); write out_pre[n][c] ---
        half8 bV[2][2];
        #pragma unroll
        for (int ntd = 0; ntd < 2; ++ntd)
            #pragma unroll
            for (int ks = 0; ks < 2; ++ks)
                bV[ntd][ks] = *(const half8*)(sHalf + VTO + (h * 32 + ntd * 16 + mrow) * 72 + ks * 32 + kq * 8);
        #pragma unroll
        for (int mtq = 0; mtq < 4; ++mtq)
            #pragma unroll
            for (int ntd = 0; ntd < 2; ++ntd) {
                floatx4 o = accPV[mtq][ntd];
                o = __builtin_amdgcn_mfma_f32_16x16x32_f16(aP[mtq][0], bV[ntd][0], o, 0, 0, 0);
                o = __builtin_amdgcn_mfma_f32_16x16x32_f16(aP[mtq][1], bV[ntd][1], o, 0, 0, 0);
                int c = h * 32 + ntd * 16 + mrow;
                #pragma unroll
                for (int r = 0; r < 4; ++r)
                    sHalf[VRO + (mtq * 16 + kq * 4 + r) * 200 + c] = (_Float16)o[r];
            }
    }
    __syncthreads();   // barrier 3

    // ---------------- Phase 4: proj GEMM (M=64, N=192, K=192) ----------------
    {
        int mt = wv >> 1;
        half8 af[6];
        #pragma unroll
        for (int ks = 0; ks < 6; ++ks)
            af[ks] = *(const half8*)(sHalf + VRO + (mt * 16 + mrow) * 200 + ks * 32 + kq * 8);
        #pragma unroll 1
        for (int it = 0; it < 6; ++it) {
            int nt = (wv & 1) * 6 + it;
            int ncol = nt * 16 + mrow;
            half8 bf[6];
            #pragma unroll
            for (int ks = 0; ks < 6; ++ks)
                bf[ks] = ((const half8*)PtF)[(nt * 6 + ks) * 64 + lane];
            float bv = sBias[768 + ncol];
            floatx4 acc = {bv, bv, bv, bv};
            #pragma unroll
            for (int ks = 0; ks < 6; ++ks)
                acc = __builtin_amdgcn_mfma_f32_16x16x32_f16(af[ks], bf[ks], acc, 0, 0, 0);
            int m0 = mt * 16 + kq * 4;
            #pragma unroll
            for (int r = 0; r < 4; ++r)
                sOut32[(m0 + r) * 196 + ncol] = acc[r];
        }
    }
    __syncthreads();   // barrier 4

    // ---------------- Phase 5: coalesced copy-out (float4) ----------------
    {
        float* og = outg + (size_t)b * 12288;
        #pragma unroll
        for (int it = 0; it < 6; ++it) {
            int f = it * 2048 + tid * 4;
            int n = f / 192;
            int c = f - n * 192;
            float4 v = *(const float4*)(sOut32 + n * 196 + c);
            *(float4*)(og + f) = v;
        }
    }
}

extern "C" void kernel_launch(void* const* d_in, const int* in_sizes, int n_in,
                              void* d_out, int out_size, void* d_ws, size_t ws_size,
                              hipStream_t stream) {
    (void)in_sizes; (void)n_in; (void)out_size; (void)ws_size;
    const float* x      = (const float*)d_in[0];
    const float* wq     = (const float*)d_in[1];
    const float* bq     = (const float*)d_in[2];
    const float* wkv    = (const float*)d_in[3];
    const float* bkv    = (const float*)d_in[4];
    const float* rpb    = (const float*)d_in[5];
    const int*   rel    = (const int*)d_in[6];
    const float* dw_w   = (const float*)d_in[7];
    const float* dw_b   = (const float*)d_in[8];
    const float* pw_w   = (const float*)d_in[9];
    const float* pw_b   = (const float*)d_in[10];
    const float* proj_w = (const float*)d_in[11];
    const float* proj_b = (const float*)d_in[12];

    _Float16* WtF  = (_Float16*)d_ws;
    _Float16* PtF  = (_Float16*)((char*)d_ws + 294912);
    float*    biasF= (float*)((char*)d_ws + 368640);
    _Float16* dwF  = (_Float16*)((char*)d_ws + 466944);
    _Float16* dwbF = (_Float16*)((char*)d_ws + 476544);
    _Float16* pwF  = (_Float16*)((char*)d_ws + 476928);

    prep_kernel<<<430, 512, 0, stream>>>(wq, wkv, proj_w, rpb, rel, dw_w, dw_b, pw_w,
                                         WtF, PtF, biasF, dwF, dwbF, pwF);
    wa_main<<<4096, 512, 144144, stream>>>(x, bq, bkv, proj_b, pw_b,
                                           WtF, PtF, biasF, dwF, dwbF, pwF,
                                           (float*)d_out);
}